// Round 1
// baseline (1163.187 us; speedup 1.0000x reference)
//
#include <hip/hip_runtime.h>

#define N_NODES 100000
#define N_EDGES 500000
#define M_PAD   100096   // 782 * 128
#define NCHUNK  196      // ceil(N_NODES / 512)

using f32x4  = __attribute__((ext_vector_type(4))) float;
using bf16x8 = __attribute__((ext_vector_type(8))) __bf16;

__device__ __forceinline__ ushort f2bf(float f) {
  union { float f; unsigned u; } v; v.f = f;
  unsigned r = v.u + 0x7fffu + ((v.u >> 16) & 1u);   // RNE
  return (ushort)(r >> 16);
}
__device__ __forceinline__ float bf2f(ushort b) {
  union { unsigned u; float f; } v; v.u = ((unsigned)b) << 16;
  return v.f;
}

// ---------------------------------------------------------------------------
// Conversions
// ---------------------------------------------------------------------------
__global__ __launch_bounds__(256) void cvt_x_kernel(const float* __restrict__ x,
                                                    ushort* __restrict__ h) {
  const size_t i = (size_t)blockIdx.x * 256 + threadIdx.x;  // float4 index
  ushort4 o;
  if (i < (size_t)N_NODES * 64) {
    const float4 v = ((const float4*)x)[i];
    o.x = f2bf(v.x); o.y = f2bf(v.y); o.z = f2bf(v.z); o.w = f2bf(v.w);
  } else {
    o.x = 0; o.y = 0; o.z = 0; o.w = 0;   // zero pad rows -> zero feat rows
  }
  ((ushort4*)h)[i] = o;
}

// W [le][k][n] fp32 -> Wt [le][n][k] bf16 (transpose so B-fragments read contiguous k)
__global__ __launch_bounds__(256) void cvt_w_kernel(const float* __restrict__ W,
                                                    ushort* __restrict__ Wt) {
  const int i = blockIdx.x * 256 + threadIdx.x;       // 6*65536
  const int le = i >> 16, r = i & 65535, nn = r >> 8, kk = r & 255;
  Wt[i] = f2bf(W[(le << 16) | (kk << 8) | nn]);
}

// W_out [256][349] -> Wto [384][256] bf16 transposed, zero-padded cols
__global__ __launch_bounds__(256) void cvt_wout_kernel(const float* __restrict__ Wo,
                                                       ushort* __restrict__ Wto) {
  const int i = blockIdx.x * 256 + threadIdx.x;       // 384*256
  const int nn = i >> 8, kk = i & 255;
  Wto[i] = f2bf(nn < 349 ? Wo[kk * 349 + nn] : 0.f);
}

// ---------------------------------------------------------------------------
// CSR build (by dst), per etype; dst is layer-invariant so built once per call
// ---------------------------------------------------------------------------
__global__ __launch_bounds__(256) void zero_cnt_kernel(int* __restrict__ cnt) {
  const int i = blockIdx.x * 256 + threadIdx.x;
  if (i < 3 * N_NODES) cnt[i] = 0;
}

__global__ __launch_bounds__(256) void hist_kernel(const int* __restrict__ dst,
                                                   int* __restrict__ cnt) {
  const int i = blockIdx.x * 256 + threadIdx.x;
  if (i >= 3 * N_EDGES) return;
  const int et = i / N_EDGES;
  atomicAdd(&cnt[et * N_NODES + dst[i]], 1);
}

__global__ __launch_bounds__(512) void scan1_kernel(const int* __restrict__ cnt,
                                                    int* __restrict__ rowp,
                                                    int* __restrict__ bsum) {
  __shared__ int sm[512];
  const int et = blockIdx.y, c = blockIdx.x, tid = threadIdx.x;
  const int idx = c * 512 + tid;
  const int v = (idx < N_NODES) ? cnt[et * N_NODES + idx] : 0;
  sm[tid] = v; __syncthreads();
  for (int off = 1; off < 512; off <<= 1) {
    const int tmp = (tid >= off) ? sm[tid - off] : 0;
    __syncthreads();
    sm[tid] += tmp;
    __syncthreads();
  }
  if (idx < N_NODES) rowp[et * (N_NODES + 1) + idx] = sm[tid] - v;  // exclusive
  if (tid == 511) bsum[et * NCHUNK + c] = sm[511];
}

__global__ __launch_bounds__(256) void scan2_kernel(int* __restrict__ bsum) {
  __shared__ int sm[256];
  const int et = blockIdx.x, tid = threadIdx.x;
  const int v = (tid < NCHUNK) ? bsum[et * NCHUNK + tid] : 0;
  sm[tid] = v; __syncthreads();
  for (int off = 1; off < 256; off <<= 1) {
    const int tmp = (tid >= off) ? sm[tid - off] : 0;
    __syncthreads();
    sm[tid] += tmp;
    __syncthreads();
  }
  if (tid < NCHUNK) bsum[et * NCHUNK + tid] = sm[tid] - v;          // exclusive
}

__global__ __launch_bounds__(512) void scan3_kernel(int* __restrict__ rowp,
                                                    const int* __restrict__ bsum,
                                                    int* __restrict__ cur) {
  const int et = blockIdx.y, c = blockIdx.x, tid = threadIdx.x;
  const int idx = c * 512 + tid;
  if (idx < N_NODES) {
    const int v = rowp[et * (N_NODES + 1) + idx] + bsum[et * NCHUNK + c];
    rowp[et * (N_NODES + 1) + idx] = v;
    cur[et * N_NODES + idx] = v;
  }
  if (c == 0 && tid == 0) rowp[et * (N_NODES + 1) + N_NODES] = N_EDGES;
}

__global__ __launch_bounds__(256) void scatter_kernel(const int* __restrict__ src,
                                                      const int* __restrict__ dst,
                                                      int* __restrict__ cur,
                                                      int* __restrict__ perm) {
  const int i = blockIdx.x * 256 + threadIdx.x;
  if (i >= 3 * N_EDGES) return;
  const int et = i / N_EDGES;
  const int pos = atomicAdd(&cur[et * N_NODES + dst[i]], 1);
  perm[et * N_EDGES + pos] = src[i];
}

// ---------------------------------------------------------------------------
// bf16 MFMA GEMM, 128x128 tile, BK=64, global_load_lds(16B), XOR-swizzled LDS.
// A [M_PAD][256] bf16 row-major; Bt [Ncols][256] bf16 row-major (B transposed).
// obias==nullptr: feat mode, C bf16 [m][256]. else: final mode, C fp32 [m][ldc]
// with +bias and m/n guards.
// Operand-swap trick: mfma(B_frag, A_frag) yields lane-holds-4-consecutive-n,
// enabling ushort4/float4 stores.
// ---------------------------------------------------------------------------
__global__ __launch_bounds__(256) void gemm128(const ushort* __restrict__ A,
                                               const ushort* __restrict__ Bt,
                                               void* __restrict__ Cv,
                                               const float* __restrict__ obias,
                                               int ldc, int nmax, int mmax) {
  __shared__ ushort As[128 * 64];
  __shared__ ushort Bs[128 * 64];
  const int t = threadIdx.x;
  const int lane = t & 63;
  const int wave = t >> 6;
  const int wm = (wave >> 1) << 6;
  const int wn = (wave & 1) << 6;
  const int quad = lane >> 4;
  const int ln = lane & 15;
  const size_t m0 = (size_t)blockIdx.x * 128;
  const size_t n0 = (size_t)blockIdx.y * 128;

  f32x4 acc[4][4];
#pragma unroll
  for (int x = 0; x < 4; ++x)
#pragma unroll
    for (int y = 0; y < 4; ++y)
      acc[x][y] = (f32x4){0.f, 0.f, 0.f, 0.f};

  for (int k0 = 0; k0 < 256; k0 += 64) {
    __syncthreads();
#pragma unroll
    for (int i = 0; i < 4; ++i) {
      const int f = i * 256 + t;
      const int row = f >> 3;
      const int cl = (f & 7) ^ (row & 7);                 // global-side swizzle
      const int ldsbase = (i * 256 + (t & ~63)) << 3;     // wave-uniform, ushort idx
      __builtin_amdgcn_global_load_lds(
          (const __attribute__((address_space(1))) void*)(A + (m0 + row) * 256 + k0 + cl * 8),
          (__attribute__((address_space(3))) void*)(As + ldsbase), 16, 0, 0);
      __builtin_amdgcn_global_load_lds(
          (const __attribute__((address_space(1))) void*)(Bt + (n0 + row) * 256 + k0 + cl * 8),
          (__attribute__((address_space(3))) void*)(Bs + ldsbase), 16, 0, 0);
    }
    __syncthreads();
#pragma unroll
    for (int s = 0; s < 2; ++s) {
      bf16x8 af[4], bfr[4];
      const int cl = s * 4 + quad;
#pragma unroll
      for (int x = 0; x < 4; ++x) {
        const int mm = wm + x * 16 + ln;
        af[x] = *(const bf16x8*)(As + mm * 64 + ((cl ^ (mm & 7)) << 3));
        const int nn = wn + x * 16 + ln;
        bfr[x] = *(const bf16x8*)(Bs + nn * 64 + ((cl ^ (nn & 7)) << 3));
      }
#pragma unroll
      for (int x = 0; x < 4; ++x)
#pragma unroll
        for (int y = 0; y < 4; ++y)
          acc[x][y] = __builtin_amdgcn_mfma_f32_16x16x32_bf16(bfr[y], af[x], acc[x][y], 0, 0, 0);
    }
  }

  if (!obias) {
    ushort* C = (ushort*)Cv;
#pragma unroll
    for (int x = 0; x < 4; ++x) {
      const size_t m = m0 + wm + x * 16 + ln;
#pragma unroll
      for (int y = 0; y < 4; ++y) {
        const size_t n = n0 + wn + y * 16 + quad * 4;
        ushort4 o;
        o.x = f2bf(acc[x][y][0]); o.y = f2bf(acc[x][y][1]);
        o.z = f2bf(acc[x][y][2]); o.w = f2bf(acc[x][y][3]);
        *(ushort4*)(C + m * 256 + n) = o;
      }
    }
  } else {
    float* C = (float*)Cv;
#pragma unroll
    for (int x = 0; x < 4; ++x) {
      const int m = (int)m0 + wm + x * 16 + ln;
      if (m < mmax) {
#pragma unroll
        for (int y = 0; y < 4; ++y) {
          const int n = (int)n0 + wn + y * 16 + quad * 4;
#pragma unroll
          for (int r = 0; r < 4; ++r)
            if (n + r < nmax)
              C[(size_t)m * ldc + n + r] = acc[x][y][r] + obias[n + r];
        }
      }
    }
  }
}

// ---------------------------------------------------------------------------
// el/er: one wave per (node, etype). el[n,h] = dot(feat[n,h,:], attn_l[h,:])
// ---------------------------------------------------------------------------
__global__ __launch_bounds__(256) void eler_kernel(const ushort* __restrict__ feat,
                                                   const float* __restrict__ attn_l,
                                                   const float* __restrict__ attn_r,
                                                   float* __restrict__ el,
                                                   float* __restrict__ er, int layer) {
  const int et = blockIdx.y;
  const int wave = threadIdx.x >> 6, lane = threadIdx.x & 63;
  const int n = blockIdx.x * 4 + wave;
  const int h = lane >> 4, dd = (lane & 15) << 2;
  const ushort* f = feat + ((size_t)et * M_PAD + n) * 256 + (lane << 2);
  const float* al = attn_l + (((layer * 3 + et) * 4 + h) << 6) + dd;
  const float* ar = attn_r + (((layer * 3 + et) * 4 + h) << 6) + dd;
  const ushort4 fv = *(const ushort4*)f;
  const float v0 = bf2f(fv.x), v1 = bf2f(fv.y), v2 = bf2f(fv.z), v3 = bf2f(fv.w);
  float pl = v0 * al[0] + v1 * al[1] + v2 * al[2] + v3 * al[3];
  float pr = v0 * ar[0] + v1 * ar[1] + v2 * ar[2] + v3 * ar[3];
#pragma unroll
  for (int off = 8; off >= 1; off >>= 1) {
    pl += __shfl_down(pl, off, 16);
    pr += __shfl_down(pr, off, 16);
  }
  if ((lane & 15) == 0) {
    el[((size_t)et * N_NODES + n) * 4 + h] = pl;
    er[((size_t)et * N_NODES + n) * 4 + h] = pr;
  }
}

// ---------------------------------------------------------------------------
// Aggregation: one wave per node, all 3 etypes fused. Single pass per etype:
// agg = (sum w*feat) / (sum w), w = exp(leaky_relu(el[s]+er[n])). No segment
// max needed (logits bounded), no atomics (CSR). Writes next-layer h in bf16
// with fused ReLU (layer 0) — pad rows keep their zeros from cvt_x.
// ---------------------------------------------------------------------------
__global__ __launch_bounds__(256) void agg_kernel(const ushort* __restrict__ feat,
                                                  const float* __restrict__ el,
                                                  const float* __restrict__ er,
                                                  const int* __restrict__ rowp,
                                                  const int* __restrict__ perm,
                                                  const float* __restrict__ bias,
                                                  ushort* __restrict__ hout,
                                                  int layer, int do_relu) {
  const int wave = threadIdx.x >> 6, lane = threadIdx.x & 63;
  const int n = blockIdx.x * 4 + wave;
  const int h = lane >> 4;
  const float* bl = bias + layer * 768 + (lane << 2);
  float a0 = bl[0] + bl[256] + bl[512];
  float a1 = bl[1] + bl[257] + bl[513];
  float a2 = bl[2] + bl[258] + bl[514];
  float a3 = bl[3] + bl[259] + bl[515];
#pragma unroll
  for (int et = 0; et < 3; ++et) {
    const int beg = rowp[et * (N_NODES + 1) + n];
    const int end = rowp[et * (N_NODES + 1) + n + 1];
    if (end == beg) continue;                       // avoid 0/0 on isolated nodes
    const float ern = er[((size_t)et * N_NODES + n) * 4 + h];
    const float* ele = el + (size_t)et * N_NODES * 4;
    const ushort* fb = feat + (size_t)et * M_PAD * 256;
    const int* ps = perm + (size_t)et * N_EDGES;
    float l0 = 0.f, l1 = 0.f, l2 = 0.f, l3 = 0.f, den = 0.f;
    for (int i = beg; i < end; ++i) {
      const int s = ps[i];
      float z = ele[s * 4 + h] + ern;
      z = (z > 0.f) ? z : 0.2f * z;
      const float w = __expf(z);
      den += w;
      const ushort4 fv = *(const ushort4*)(fb + (size_t)s * 256 + (lane << 2));
      l0 += w * bf2f(fv.x); l1 += w * bf2f(fv.y);
      l2 += w * bf2f(fv.z); l3 += w * bf2f(fv.w);
    }
    const float inv = 1.0f / den;
    a0 += l0 * inv; a1 += l1 * inv; a2 += l2 * inv; a3 += l3 * inv;
  }
  if (do_relu) {
    a0 = fmaxf(a0, 0.f); a1 = fmaxf(a1, 0.f);
    a2 = fmaxf(a2, 0.f); a3 = fmaxf(a3, 0.f);
  }
  ushort4 o;
  o.x = f2bf(a0); o.y = f2bf(a1); o.z = f2bf(a2); o.w = f2bf(a3);
  *(ushort4*)(hout + (size_t)n * 256 + (lane << 2)) = o;
}

// ---------------------------------------------------------------------------
extern "C" void kernel_launch(void* const* d_in, const int* in_sizes, int n_in,
                              void* d_out, int out_size, void* d_ws, size_t ws_size,
                              hipStream_t stream) {
  const float* x      = (const float*)d_in[0];
  const float* W      = (const float*)d_in[1];
  const float* attn_l = (const float*)d_in[2];
  const float* attn_r = (const float*)d_in[3];
  const float* bias   = (const float*)d_in[4];
  const float* W_out  = (const float*)d_in[5];
  const float* b_out  = (const float*)d_in[6];
  const int*   src    = (const int*)d_in[7];
  const int*   dst    = (const int*)d_in[8];

  char* p = (char*)d_ws;
  auto carve = [&](size_t bytes) {
    char* r = p;
    p += (bytes + 255) & ~(size_t)255;
    return r;
  };
  ushort* h_bf  = (ushort*)carve((size_t)M_PAD * 256 * 2);        //  51.2 MB
  ushort* feat  = (ushort*)carve((size_t)3 * M_PAD * 256 * 2);    // 153.7 MB
  ushort* Wt    = (ushort*)carve((size_t)6 * 65536 * 2);
  ushort* Wto   = (ushort*)carve((size_t)384 * 256 * 2);
  float*  el    = (float*)carve((size_t)3 * N_NODES * 4 * 4);
  float*  er    = (float*)carve((size_t)3 * N_NODES * 4 * 4);
  int*    cnt   = (int*)carve((size_t)3 * N_NODES * 4);
  int*    rowp  = (int*)carve((size_t)3 * (N_NODES + 1) * 4);
  int*    cur   = (int*)carve((size_t)3 * N_NODES * 4);
  int*    perm  = (int*)carve((size_t)3 * N_EDGES * 4);
  int*    bsum  = (int*)carve((size_t)3 * NCHUNK * 4);

  // input conversions (pad rows of h_bf zeroed -> zero feat pad rows)
  cvt_x_kernel<<<M_PAD * 64 / 256, 256, 0, stream>>>(x, h_bf);
  cvt_w_kernel<<<6 * 65536 / 256, 256, 0, stream>>>(W, Wt);
  cvt_wout_kernel<<<384 * 256 / 256, 256, 0, stream>>>(W_out, Wto);

  // CSR by dst (shared across layers)
  zero_cnt_kernel<<<(3 * N_NODES + 255) / 256, 256, 0, stream>>>(cnt);
  hist_kernel<<<(3 * N_EDGES + 255) / 256, 256, 0, stream>>>(dst, cnt);
  scan1_kernel<<<dim3(NCHUNK, 3), 512, 0, stream>>>(cnt, rowp, bsum);
  scan2_kernel<<<3, 256, 0, stream>>>(bsum);
  scan3_kernel<<<dim3(NCHUNK, 3), 512, 0, stream>>>(rowp, bsum, cur);
  scatter_kernel<<<(3 * N_EDGES + 255) / 256, 256, 0, stream>>>(src, dst, cur, perm);

  const dim3 gfeat(M_PAD / 128, 2);
  for (int l = 0; l < 2; ++l) {
    for (int e = 0; e < 3; ++e)
      gemm128<<<gfeat, 256, 0, stream>>>(h_bf, Wt + (size_t)(l * 3 + e) * 65536,
                                         feat + (size_t)e * M_PAD * 256,
                                         nullptr, 256, 0, 0);
    eler_kernel<<<dim3(N_NODES / 4, 3), 256, 0, stream>>>(feat, attn_l, attn_r, el, er, l);
    agg_kernel<<<N_NODES / 4, 256, 0, stream>>>(feat, el, er, rowp, perm, bias,
                                                h_bf, l, l == 0 ? 1 : 0);
  }
  // final classifier GEMM, fp32 out + bias, guarded to [100000, 349]
  gemm128<<<dim3(M_PAD / 128, 3), 256, 0, stream>>>(h_bf, Wto, d_out, b_out,
                                                    349, 349, N_NODES);
}

// Round 2
// 1137.117 us; speedup vs baseline: 1.0229x; 1.0229x over previous
//
#include <hip/hip_runtime.h>

#define N_NODES 100000
#define N_EDGES 500000
#define M_PAD   100096   // 782 * 128
#define NCHUNK  196      // ceil(N_NODES / 512)

using f32x4  = __attribute__((ext_vector_type(4))) float;
using bf16x8 = __attribute__((ext_vector_type(8))) __bf16;

__device__ __forceinline__ ushort f2bf(float f) {
  union { float f; unsigned u; } v; v.f = f;
  unsigned r = v.u + 0x7fffu + ((v.u >> 16) & 1u);   // RNE
  return (ushort)(r >> 16);
}
__device__ __forceinline__ float bf2f(ushort b) {
  union { unsigned u; float f; } v; v.u = ((unsigned)b) << 16;
  return v.f;
}

// ---------------------------------------------------------------------------
// Conversions
// ---------------------------------------------------------------------------
__global__ __launch_bounds__(256) void cvt_x_kernel(const float* __restrict__ x,
                                                    ushort* __restrict__ h) {
  const size_t i = (size_t)blockIdx.x * 256 + threadIdx.x;  // float4 index
  ushort4 o;
  if (i < (size_t)N_NODES * 64) {
    const float4 v = ((const float4*)x)[i];
    o.x = f2bf(v.x); o.y = f2bf(v.y); o.z = f2bf(v.z); o.w = f2bf(v.w);
  } else {
    o.x = 0; o.y = 0; o.z = 0; o.w = 0;   // zero pad rows -> zero feat rows
  }
  ((ushort4*)h)[i] = o;
}

// W [le][k][n] fp32 -> Wt [le][n][k] bf16
__global__ __launch_bounds__(256) void cvt_w_kernel(const float* __restrict__ W,
                                                    ushort* __restrict__ Wt) {
  const int i = blockIdx.x * 256 + threadIdx.x;       // 6*65536
  const int le = i >> 16, r = i & 65535, nn = r >> 8, kk = r & 255;
  Wt[i] = f2bf(W[(le << 16) | (kk << 8) | nn]);
}

// W_out [256][349] -> Wto [384][256] bf16 transposed, zero-padded cols
__global__ __launch_bounds__(256) void cvt_wout_kernel(const float* __restrict__ Wo,
                                                       ushort* __restrict__ Wto) {
  const int i = blockIdx.x * 256 + threadIdx.x;       // 384*256
  const int nn = i >> 8, kk = i & 255;
  Wto[i] = f2bf(nn < 349 ? Wo[kk * 349 + nn] : 0.f);
}

// ---------------------------------------------------------------------------
// CSR build (by dst), per etype; dst is layer-invariant so built once per call
// ---------------------------------------------------------------------------
__global__ __launch_bounds__(256) void zero_cnt_kernel(int* __restrict__ cnt) {
  const int i = blockIdx.x * 256 + threadIdx.x;
  if (i < 3 * N_NODES) cnt[i] = 0;
}

__global__ __launch_bounds__(256) void hist_kernel(const int* __restrict__ dst,
                                                   int* __restrict__ cnt) {
  const int i = blockIdx.x * 256 + threadIdx.x;
  if (i >= 3 * N_EDGES) return;
  const int et = i / N_EDGES;
  atomicAdd(&cnt[et * N_NODES + dst[i]], 1);
}

__global__ __launch_bounds__(512) void scan1_kernel(const int* __restrict__ cnt,
                                                    int* __restrict__ rowp,
                                                    int* __restrict__ bsum) {
  __shared__ int sm[512];
  const int et = blockIdx.y, c = blockIdx.x, tid = threadIdx.x;
  const int idx = c * 512 + tid;
  const int v = (idx < N_NODES) ? cnt[et * N_NODES + idx] : 0;
  sm[tid] = v; __syncthreads();
  for (int off = 1; off < 512; off <<= 1) {
    const int tmp = (tid >= off) ? sm[tid - off] : 0;
    __syncthreads();
    sm[tid] += tmp;
    __syncthreads();
  }
  if (idx < N_NODES) rowp[et * (N_NODES + 1) + idx] = sm[tid] - v;  // exclusive
  if (tid == 511) bsum[et * NCHUNK + c] = sm[511];
}

__global__ __launch_bounds__(256) void scan2_kernel(int* __restrict__ bsum) {
  __shared__ int sm[256];
  const int et = blockIdx.x, tid = threadIdx.x;
  const int v = (tid < NCHUNK) ? bsum[et * NCHUNK + tid] : 0;
  sm[tid] = v; __syncthreads();
  for (int off = 1; off < 256; off <<= 1) {
    const int tmp = (tid >= off) ? sm[tid - off] : 0;
    __syncthreads();
    sm[tid] += tmp;
    __syncthreads();
  }
  if (tid < NCHUNK) bsum[et * NCHUNK + tid] = sm[tid] - v;          // exclusive
}

__global__ __launch_bounds__(512) void scan3_kernel(int* __restrict__ rowp,
                                                    const int* __restrict__ bsum,
                                                    int* __restrict__ cur) {
  const int et = blockIdx.y, c = blockIdx.x, tid = threadIdx.x;
  const int idx = c * 512 + tid;
  if (idx < N_NODES) {
    const int v = rowp[et * (N_NODES + 1) + idx] + bsum[et * NCHUNK + c];
    rowp[et * (N_NODES + 1) + idx] = v;
    cur[et * N_NODES + idx] = v;
  }
  if (c == 0 && tid == 0) rowp[et * (N_NODES + 1) + N_NODES] = N_EDGES;
}

__global__ __launch_bounds__(256) void scatter_kernel(const int* __restrict__ src,
                                                      const int* __restrict__ dst,
                                                      int* __restrict__ cur,
                                                      int* __restrict__ perm) {
  const int i = blockIdx.x * 256 + threadIdx.x;
  if (i >= 3 * N_EDGES) return;
  const int et = i / N_EDGES;
  const int pos = atomicAdd(&cur[et * N_NODES + dst[i]], 1);
  perm[et * N_EDGES + pos] = src[i];
}

// ---------------------------------------------------------------------------
// Fused feat GEMM: one block does a 128(m)x128(n) tile for ALL 3 etypes,
// sharing the A tile (3x less A traffic, 3x MFMA per staging barrier on this
// short-K shape). Epilogue writes feat (bf16) AND el/er: each wave's 64-wide
// n-chunk is exactly one head, so el[n,h]=dot(feat[n,h,:],al[h,:]) reduces
// with two shfl_xor over quads — no atomics, no eler kernel.
// acc[3][4][4] f32x4 = 192 VGPRs -> __launch_bounds__(256,2) (2 waves/SIMD).
// ---------------------------------------------------------------------------
__global__ __launch_bounds__(256, 2) void gemm_feat_fused(
    const ushort* __restrict__ A, const ushort* __restrict__ WtL,
    ushort* __restrict__ feat, const float* __restrict__ attn_l,
    const float* __restrict__ attn_r, float* __restrict__ el,
    float* __restrict__ er, int layer) {
  __shared__ ushort As[128 * 64];
  __shared__ ushort Bs[3 * 128 * 64];
  const int t = threadIdx.x;
  const int lane = t & 63;
  const int wave = t >> 6;
  const int wm = (wave >> 1) << 6;
  const int wn = (wave & 1) << 6;
  const int quad = lane >> 4;
  const int ln = lane & 15;
  const size_t m0 = (size_t)blockIdx.x * 128;
  const size_t n0 = (size_t)blockIdx.y * 128;

  f32x4 acc[3][4][4];
#pragma unroll
  for (int e = 0; e < 3; ++e)
#pragma unroll
    for (int x = 0; x < 4; ++x)
#pragma unroll
      for (int y = 0; y < 4; ++y)
        acc[e][x][y] = (f32x4){0.f, 0.f, 0.f, 0.f};

  for (int k0 = 0; k0 < 256; k0 += 64) {
    __syncthreads();
#pragma unroll
    for (int i = 0; i < 4; ++i) {
      const int f = i * 256 + t;
      const int row = f >> 3;
      const int cl = (f & 7) ^ (row & 7);                 // global-side swizzle
      const int ldsbase = (i * 256 + (t & ~63)) << 3;     // wave-uniform, ushort idx
      __builtin_amdgcn_global_load_lds(
          (const __attribute__((address_space(1))) void*)(A + (m0 + row) * 256 + k0 + cl * 8),
          (__attribute__((address_space(3))) void*)(As + ldsbase), 16, 0, 0);
#pragma unroll
      for (int e = 0; e < 3; ++e)
        __builtin_amdgcn_global_load_lds(
            (const __attribute__((address_space(1))) void*)(WtL + (e << 16) + (n0 + row) * 256 + k0 + cl * 8),
            (__attribute__((address_space(3))) void*)(Bs + e * 8192 + ldsbase), 16, 0, 0);
    }
    __syncthreads();
#pragma unroll
    for (int s = 0; s < 2; ++s) {
      const int cl = s * 4 + quad;
      bf16x8 af[4];
#pragma unroll
      for (int x = 0; x < 4; ++x) {
        const int mm = wm + x * 16 + ln;
        af[x] = *(const bf16x8*)(As + mm * 64 + ((cl ^ (mm & 7)) << 3));
      }
#pragma unroll
      for (int e = 0; e < 3; ++e) {
        bf16x8 bfr[4];
#pragma unroll
        for (int y = 0; y < 4; ++y) {
          const int nn = wn + y * 16 + ln;
          bfr[y] = *(const bf16x8*)(Bs + e * 8192 + nn * 64 + ((cl ^ (nn & 7)) << 3));
        }
#pragma unroll
        for (int x = 0; x < 4; ++x)
#pragma unroll
          for (int y = 0; y < 4; ++y)
            acc[e][x][y] = __builtin_amdgcn_mfma_f32_16x16x32_bf16(bfr[y], af[x], acc[e][x][y], 0, 0, 0);
      }
    }
  }

  const int h = (int)(n0 + wn) >> 6;                      // this wave's head
#pragma unroll
  for (int e = 0; e < 3; ++e) {
    // feat store (bf16, [et][node][256])
    ushort* C = feat + (size_t)e * M_PAD * 256;
#pragma unroll
    for (int x = 0; x < 4; ++x) {
      const size_t m = m0 + wm + x * 16 + ln;
#pragma unroll
      for (int y = 0; y < 4; ++y) {
        const size_t n = n0 + wn + y * 16 + quad * 4;
        ushort4 o;
        o.x = f2bf(acc[e][x][y][0]); o.y = f2bf(acc[e][x][y][1]);
        o.z = f2bf(acc[e][x][y][2]); o.w = f2bf(acc[e][x][y][3]);
        *(ushort4*)(C + m * 256 + n) = o;
      }
    }
    // el/er: full head-dot from acc; d = y*16 + quad*4 + r
    const float* al = attn_l + (((layer * 3 + e) * 4 + h) << 6);
    const float* ar = attn_r + (((layer * 3 + e) * 4 + h) << 6);
    float4 alv[4], arv[4];
#pragma unroll
    for (int y = 0; y < 4; ++y) {
      alv[y] = *(const float4*)(al + y * 16 + quad * 4);
      arv[y] = *(const float4*)(ar + y * 16 + quad * 4);
    }
#pragma unroll
    for (int x = 0; x < 4; ++x) {
      float pl = 0.f, pr = 0.f;
#pragma unroll
      for (int y = 0; y < 4; ++y) {
        pl += acc[e][x][y][0] * alv[y].x + acc[e][x][y][1] * alv[y].y +
              acc[e][x][y][2] * alv[y].z + acc[e][x][y][3] * alv[y].w;
        pr += acc[e][x][y][0] * arv[y].x + acc[e][x][y][1] * arv[y].y +
              acc[e][x][y][2] * arv[y].z + acc[e][x][y][3] * arv[y].w;
      }
      pl += __shfl_xor(pl, 16); pl += __shfl_xor(pl, 32);
      pr += __shfl_xor(pr, 16); pr += __shfl_xor(pr, 32);
      const int m = (int)m0 + wm + x * 16 + ln;
      if (quad == 0 && m < N_NODES) {
        el[((size_t)e * N_NODES + m) * 4 + h] = pl;
        er[((size_t)e * N_NODES + m) * 4 + h] = pr;
      }
    }
  }
}

// ---------------------------------------------------------------------------
// Final classifier GEMM (fp32 out + bias, guarded). Same structure as R0.
// ---------------------------------------------------------------------------
__global__ __launch_bounds__(256) void gemm128(const ushort* __restrict__ A,
                                               const ushort* __restrict__ Bt,
                                               float* __restrict__ C,
                                               const float* __restrict__ obias,
                                               int ldc, int nmax, int mmax) {
  __shared__ ushort As[128 * 64];
  __shared__ ushort Bs[128 * 64];
  const int t = threadIdx.x;
  const int lane = t & 63;
  const int wave = t >> 6;
  const int wm = (wave >> 1) << 6;
  const int wn = (wave & 1) << 6;
  const int quad = lane >> 4;
  const int ln = lane & 15;
  const size_t m0 = (size_t)blockIdx.x * 128;
  const size_t n0 = (size_t)blockIdx.y * 128;

  f32x4 acc[4][4];
#pragma unroll
  for (int x = 0; x < 4; ++x)
#pragma unroll
    for (int y = 0; y < 4; ++y)
      acc[x][y] = (f32x4){0.f, 0.f, 0.f, 0.f};

  for (int k0 = 0; k0 < 256; k0 += 64) {
    __syncthreads();
#pragma unroll
    for (int i = 0; i < 4; ++i) {
      const int f = i * 256 + t;
      const int row = f >> 3;
      const int cl = (f & 7) ^ (row & 7);
      const int ldsbase = (i * 256 + (t & ~63)) << 3;
      __builtin_amdgcn_global_load_lds(
          (const __attribute__((address_space(1))) void*)(A + (m0 + row) * 256 + k0 + cl * 8),
          (__attribute__((address_space(3))) void*)(As + ldsbase), 16, 0, 0);
      __builtin_amdgcn_global_load_lds(
          (const __attribute__((address_space(1))) void*)(Bt + (n0 + row) * 256 + k0 + cl * 8),
          (__attribute__((address_space(3))) void*)(Bs + ldsbase), 16, 0, 0);
    }
    __syncthreads();
#pragma unroll
    for (int s = 0; s < 2; ++s) {
      bf16x8 af[4], bfr[4];
      const int cl = s * 4 + quad;
#pragma unroll
      for (int x = 0; x < 4; ++x) {
        const int mm = wm + x * 16 + ln;
        af[x] = *(const bf16x8*)(As + mm * 64 + ((cl ^ (mm & 7)) << 3));
        const int nn = wn + x * 16 + ln;
        bfr[x] = *(const bf16x8*)(Bs + nn * 64 + ((cl ^ (nn & 7)) << 3));
      }
#pragma unroll
      for (int x = 0; x < 4; ++x)
#pragma unroll
        for (int y = 0; y < 4; ++y)
          acc[x][y] = __builtin_amdgcn_mfma_f32_16x16x32_bf16(bfr[y], af[x], acc[x][y], 0, 0, 0);
    }
  }

#pragma unroll
  for (int x = 0; x < 4; ++x) {
    const int m = (int)m0 + wm + x * 16 + ln;
    if (m < mmax) {
#pragma unroll
      for (int y = 0; y < 4; ++y) {
        const int n = (int)n0 + wn + y * 16 + quad * 4;
#pragma unroll
        for (int r = 0; r < 4; ++r)
          if (n + r < nmax)
            C[(size_t)m * ldc + n + r] = acc[x][y][r] + obias[n + r];
      }
    }
  }
}

// ---------------------------------------------------------------------------
// Aggregation: one wave per node, 3 etypes fused, chunk-8 software pipeline:
// 8 perm loads -> 8 independent el gathers + 8 independent feat-row gathers
// in flight (wave-uniform guards), then compute. agg=(sum w*feat)/(sum w).
// ---------------------------------------------------------------------------
__global__ __launch_bounds__(256) void agg_kernel(const ushort* __restrict__ feat,
                                                  const float* __restrict__ el,
                                                  const float* __restrict__ er,
                                                  const int* __restrict__ rowp,
                                                  const int* __restrict__ perm,
                                                  const float* __restrict__ bias,
                                                  ushort* __restrict__ hout,
                                                  int layer, int do_relu) {
  const int wave = threadIdx.x >> 6, lane = threadIdx.x & 63;
  const int n = blockIdx.x * 4 + wave;
  const int h = lane >> 4;
  const float* bl = bias + layer * 768 + (lane << 2);
  float a0 = bl[0] + bl[256] + bl[512];
  float a1 = bl[1] + bl[257] + bl[513];
  float a2 = bl[2] + bl[258] + bl[514];
  float a3 = bl[3] + bl[259] + bl[515];
#pragma unroll
  for (int et = 0; et < 3; ++et) {
    const int beg = rowp[et * (N_NODES + 1) + n];
    const int end = rowp[et * (N_NODES + 1) + n + 1];
    if (end == beg) continue;                       // avoid 0/0 on isolated nodes
    const float ern = er[((size_t)et * N_NODES + n) * 4 + h];
    const float* ele = el + (size_t)et * N_NODES * 4;
    const ushort* fb = feat + (size_t)et * M_PAD * 256;
    const int* ps = perm + (size_t)et * N_EDGES;
    float l0 = 0.f, l1 = 0.f, l2 = 0.f, l3 = 0.f, den = 0.f;
    for (int i = beg; i < end; i += 8) {
      const int c = end - i;
      int sj[8]; float ej[8]; ushort4 fvj[8];
#pragma unroll
      for (int j = 0; j < 8; ++j)
        sj[j] = (j < c) ? ps[i + j] : 0;
#pragma unroll
      for (int j = 0; j < 8; ++j)
        ej[j] = (j < c) ? ele[sj[j] * 4 + h] : 0.f;
#pragma unroll
      for (int j = 0; j < 8; ++j)
        if (j < c) fvj[j] = *(const ushort4*)(fb + (size_t)sj[j] * 256 + (lane << 2));
#pragma unroll
      for (int j = 0; j < 8; ++j)
        if (j < c) {
          float z = ej[j] + ern;
          z = (z > 0.f) ? z : 0.2f * z;
          const float w = __expf(z);
          den += w;
          l0 += w * bf2f(fvj[j].x); l1 += w * bf2f(fvj[j].y);
          l2 += w * bf2f(fvj[j].z); l3 += w * bf2f(fvj[j].w);
        }
    }
    const float inv = 1.0f / den;
    a0 += l0 * inv; a1 += l1 * inv; a2 += l2 * inv; a3 += l3 * inv;
  }
  if (do_relu) {
    a0 = fmaxf(a0, 0.f); a1 = fmaxf(a1, 0.f);
    a2 = fmaxf(a2, 0.f); a3 = fmaxf(a3, 0.f);
  }
  ushort4 o;
  o.x = f2bf(a0); o.y = f2bf(a1); o.z = f2bf(a2); o.w = f2bf(a3);
  *(ushort4*)(hout + (size_t)n * 256 + (lane << 2)) = o;
}

// ---------------------------------------------------------------------------
extern "C" void kernel_launch(void* const* d_in, const int* in_sizes, int n_in,
                              void* d_out, int out_size, void* d_ws, size_t ws_size,
                              hipStream_t stream) {
  const float* x      = (const float*)d_in[0];
  const float* W      = (const float*)d_in[1];
  const float* attn_l = (const float*)d_in[2];
  const float* attn_r = (const float*)d_in[3];
  const float* bias   = (const float*)d_in[4];
  const float* W_out  = (const float*)d_in[5];
  const float* b_out  = (const float*)d_in[6];
  const int*   src    = (const int*)d_in[7];
  const int*   dst    = (const int*)d_in[8];

  char* p = (char*)d_ws;
  auto carve = [&](size_t bytes) {
    char* r = p;
    p += (bytes + 255) & ~(size_t)255;
    return r;
  };
  ushort* h_bf  = (ushort*)carve((size_t)M_PAD * 256 * 2);        //  51.2 MB
  ushort* feat  = (ushort*)carve((size_t)3 * M_PAD * 256 * 2);    // 153.7 MB
  ushort* Wt    = (ushort*)carve((size_t)6 * 65536 * 2);
  ushort* Wto   = (ushort*)carve((size_t)384 * 256 * 2);
  float*  el    = (float*)carve((size_t)3 * N_NODES * 4 * 4);
  float*  er    = (float*)carve((size_t)3 * N_NODES * 4 * 4);
  int*    cnt   = (int*)carve((size_t)3 * N_NODES * 4);
  int*    rowp  = (int*)carve((size_t)3 * (N_NODES + 1) * 4);
  int*    cur   = (int*)carve((size_t)3 * N_NODES * 4);
  int*    perm  = (int*)carve((size_t)3 * N_EDGES * 4);
  int*    bsum  = (int*)carve((size_t)3 * NCHUNK * 4);

  cvt_x_kernel<<<M_PAD * 64 / 256, 256, 0, stream>>>(x, h_bf);
  cvt_w_kernel<<<6 * 65536 / 256, 256, 0, stream>>>(W, Wt);
  cvt_wout_kernel<<<384 * 256 / 256, 256, 0, stream>>>(W_out, Wto);

  zero_cnt_kernel<<<(3 * N_NODES + 255) / 256, 256, 0, stream>>>(cnt);
  hist_kernel<<<(3 * N_EDGES + 255) / 256, 256, 0, stream>>>(dst, cnt);
  scan1_kernel<<<dim3(NCHUNK, 3), 512, 0, stream>>>(cnt, rowp, bsum);
  scan2_kernel<<<3, 256, 0, stream>>>(bsum);
  scan3_kernel<<<dim3(NCHUNK, 3), 512, 0, stream>>>(rowp, bsum, cur);
  scatter_kernel<<<(3 * N_EDGES + 255) / 256, 256, 0, stream>>>(src, dst, cur, perm);

  for (int l = 0; l < 2; ++l) {
    gemm_feat_fused<<<dim3(M_PAD / 128, 2), 256, 0, stream>>>(
        h_bf, Wt + (size_t)l * 3 * 65536, feat, attn_l, attn_r, el, er, l);
    agg_kernel<<<N_NODES / 4, 256, 0, stream>>>(feat, el, er, rowp, perm, bias,
                                                h_bf, l, l == 0 ? 1 : 0);
  }
  gemm128<<<dim3(M_PAD / 128, 3), 256, 0, stream>>>(h_bf, Wto, (float*)d_out,
                                                    b_out, 349, 349, N_NODES);
}

// Round 3
// 953.249 us; speedup vs baseline: 1.2202x; 1.1929x over previous
//
#include <hip/hip_runtime.h>
#include <hip/hip_fp16.h>

#define N_NODES 100000
#define N_EDGES 500000
#define M_PAD   100096   // 782 * 128
#define NCHUNK  196      // ceil(N_NODES / 512)

using f32x4  = __attribute__((ext_vector_type(4))) float;
using bf16x8 = __attribute__((ext_vector_type(8))) __bf16;

__device__ __forceinline__ ushort f2bf(float f) {
  union { float f; unsigned u; } v; v.f = f;
  unsigned r = v.u + 0x7fffu + ((v.u >> 16) & 1u);   // RNE
  return (ushort)(r >> 16);
}
__device__ __forceinline__ float bf2f(ushort b) {
  union { unsigned u; float f; } v; v.u = ((unsigned)b) << 16;
  return v.f;
}

// ---------------------------------------------------------------------------
// Conversions
// ---------------------------------------------------------------------------
__global__ __launch_bounds__(256) void cvt_x_kernel(const float* __restrict__ x,
                                                    ushort* __restrict__ h) {
  const size_t i = (size_t)blockIdx.x * 256 + threadIdx.x;  // float4 index
  ushort4 o;
  if (i < (size_t)N_NODES * 64) {
    const float4 v = ((const float4*)x)[i];
    o.x = f2bf(v.x); o.y = f2bf(v.y); o.z = f2bf(v.z); o.w = f2bf(v.w);
  } else {
    o.x = 0; o.y = 0; o.z = 0; o.w = 0;   // zero pad rows -> zero feat rows
  }
  ((ushort4*)h)[i] = o;
}

// W [le][k][n] fp32 -> Wt [le][n][k] bf16
__global__ __launch_bounds__(256) void cvt_w_kernel(const float* __restrict__ W,
                                                    ushort* __restrict__ Wt) {
  const int i = blockIdx.x * 256 + threadIdx.x;       // 6*65536
  const int le = i >> 16, r = i & 65535, nn = r >> 8, kk = r & 255;
  Wt[i] = f2bf(W[(le << 16) | (kk << 8) | nn]);
}

// W_out [256][349] -> Wto [384][256] bf16 transposed, zero-padded cols
__global__ __launch_bounds__(256) void cvt_wout_kernel(const float* __restrict__ Wo,
                                                       ushort* __restrict__ Wto) {
  const int i = blockIdx.x * 256 + threadIdx.x;       // 384*256
  const int nn = i >> 8, kk = i & 255;
  Wto[i] = f2bf(nn < 349 ? Wo[kk * 349 + nn] : 0.f);
}

// ---------------------------------------------------------------------------
// CSR build (by dst), per etype; dst is layer-invariant so built once per call
// ---------------------------------------------------------------------------
__global__ __launch_bounds__(256) void zero_cnt_kernel(int* __restrict__ cnt) {
  const int i = blockIdx.x * 256 + threadIdx.x;
  if (i < 3 * N_NODES) cnt[i] = 0;
}

__global__ __launch_bounds__(256) void hist_kernel(const int* __restrict__ dst,
                                                   int* __restrict__ cnt) {
  const int i = blockIdx.x * 256 + threadIdx.x;
  if (i >= 3 * N_EDGES) return;
  const int et = i / N_EDGES;
  atomicAdd(&cnt[et * N_NODES + dst[i]], 1);
}

__global__ __launch_bounds__(512) void scan1_kernel(const int* __restrict__ cnt,
                                                    int* __restrict__ rowp,
                                                    int* __restrict__ bsum) {
  __shared__ int sm[512];
  const int et = blockIdx.y, c = blockIdx.x, tid = threadIdx.x;
  const int idx = c * 512 + tid;
  const int v = (idx < N_NODES) ? cnt[et * N_NODES + idx] : 0;
  sm[tid] = v; __syncthreads();
  for (int off = 1; off < 512; off <<= 1) {
    const int tmp = (tid >= off) ? sm[tid - off] : 0;
    __syncthreads();
    sm[tid] += tmp;
    __syncthreads();
  }
  if (idx < N_NODES) rowp[et * (N_NODES + 1) + idx] = sm[tid] - v;  // exclusive
  if (tid == 511) bsum[et * NCHUNK + c] = sm[511];
}

__global__ __launch_bounds__(256) void scan2_kernel(int* __restrict__ bsum) {
  __shared__ int sm[256];
  const int et = blockIdx.x, tid = threadIdx.x;
  const int v = (tid < NCHUNK) ? bsum[et * NCHUNK + tid] : 0;
  sm[tid] = v; __syncthreads();
  for (int off = 1; off < 256; off <<= 1) {
    const int tmp = (tid >= off) ? sm[tid - off] : 0;
    __syncthreads();
    sm[tid] += tmp;
    __syncthreads();
  }
  if (tid < NCHUNK) bsum[et * NCHUNK + tid] = sm[tid] - v;          // exclusive
}

__global__ __launch_bounds__(512) void scan3_kernel(int* __restrict__ rowp,
                                                    const int* __restrict__ bsum,
                                                    int* __restrict__ cur) {
  const int et = blockIdx.y, c = blockIdx.x, tid = threadIdx.x;
  const int idx = c * 512 + tid;
  if (idx < N_NODES) {
    const int v = rowp[et * (N_NODES + 1) + idx] + bsum[et * NCHUNK + c];
    rowp[et * (N_NODES + 1) + idx] = v;
    cur[et * N_NODES + idx] = v;
  }
  if (c == 0 && tid == 0) rowp[et * (N_NODES + 1) + N_NODES] = N_EDGES;
}

__global__ __launch_bounds__(256) void scatter_kernel(const int* __restrict__ src,
                                                      const int* __restrict__ dst,
                                                      int* __restrict__ cur,
                                                      int* __restrict__ perm,
                                                      int* __restrict__ dstc) {
  const int i = blockIdx.x * 256 + threadIdx.x;
  if (i >= 3 * N_EDGES) return;
  const int et = i / N_EDGES;
  const int d = dst[i];
  const int pos = atomicAdd(&cur[et * N_NODES + d], 1);
  perm[et * N_EDGES + pos] = src[i];
  dstc[et * N_EDGES + pos] = d;
}

// ---------------------------------------------------------------------------
// Fused feat GEMM (unchanged from R1): 128x128 tile for all 3 etypes, shared
// A tile; epilogue writes feat (bf16) and el/er via in-register head-dots.
// ---------------------------------------------------------------------------
__global__ __launch_bounds__(256, 2) void gemm_feat_fused(
    const ushort* __restrict__ A, const ushort* __restrict__ WtL,
    ushort* __restrict__ feat, const float* __restrict__ attn_l,
    const float* __restrict__ attn_r, float* __restrict__ el,
    float* __restrict__ er, int layer) {
  __shared__ ushort As[128 * 64];
  __shared__ ushort Bs[3 * 128 * 64];
  const int t = threadIdx.x;
  const int lane = t & 63;
  const int wave = t >> 6;
  const int wm = (wave >> 1) << 6;
  const int wn = (wave & 1) << 6;
  const int quad = lane >> 4;
  const int ln = lane & 15;
  const size_t m0 = (size_t)blockIdx.x * 128;
  const size_t n0 = (size_t)blockIdx.y * 128;

  f32x4 acc[3][4][4];
#pragma unroll
  for (int e = 0; e < 3; ++e)
#pragma unroll
    for (int x = 0; x < 4; ++x)
#pragma unroll
      for (int y = 0; y < 4; ++y)
        acc[e][x][y] = (f32x4){0.f, 0.f, 0.f, 0.f};

  for (int k0 = 0; k0 < 256; k0 += 64) {
    __syncthreads();
#pragma unroll
    for (int i = 0; i < 4; ++i) {
      const int f = i * 256 + t;
      const int row = f >> 3;
      const int cl = (f & 7) ^ (row & 7);                 // global-side swizzle
      const int ldsbase = (i * 256 + (t & ~63)) << 3;     // wave-uniform, ushort idx
      __builtin_amdgcn_global_load_lds(
          (const __attribute__((address_space(1))) void*)(A + (m0 + row) * 256 + k0 + cl * 8),
          (__attribute__((address_space(3))) void*)(As + ldsbase), 16, 0, 0);
#pragma unroll
      for (int e = 0; e < 3; ++e)
        __builtin_amdgcn_global_load_lds(
            (const __attribute__((address_space(1))) void*)(WtL + (e << 16) + (n0 + row) * 256 + k0 + cl * 8),
            (__attribute__((address_space(3))) void*)(Bs + e * 8192 + ldsbase), 16, 0, 0);
    }
    __syncthreads();
#pragma unroll
    for (int s = 0; s < 2; ++s) {
      const int cl = s * 4 + quad;
      bf16x8 af[4];
#pragma unroll
      for (int x = 0; x < 4; ++x) {
        const int mm = wm + x * 16 + ln;
        af[x] = *(const bf16x8*)(As + mm * 64 + ((cl ^ (mm & 7)) << 3));
      }
#pragma unroll
      for (int e = 0; e < 3; ++e) {
        bf16x8 bfr[4];
#pragma unroll
        for (int y = 0; y < 4; ++y) {
          const int nn = wn + y * 16 + ln;
          bfr[y] = *(const bf16x8*)(Bs + e * 8192 + nn * 64 + ((cl ^ (nn & 7)) << 3));
        }
#pragma unroll
        for (int x = 0; x < 4; ++x)
#pragma unroll
          for (int y = 0; y < 4; ++y)
            acc[e][x][y] = __builtin_amdgcn_mfma_f32_16x16x32_bf16(bfr[y], af[x], acc[e][x][y], 0, 0, 0);
      }
    }
  }

  const int h = (int)(n0 + wn) >> 6;                      // this wave's head
#pragma unroll
  for (int e = 0; e < 3; ++e) {
    ushort* C = feat + (size_t)e * M_PAD * 256;
#pragma unroll
    for (int x = 0; x < 4; ++x) {
      const size_t m = m0 + wm + x * 16 + ln;
#pragma unroll
      for (int y = 0; y < 4; ++y) {
        const size_t n = n0 + wn + y * 16 + quad * 4;
        ushort4 o;
        o.x = f2bf(acc[e][x][y][0]); o.y = f2bf(acc[e][x][y][1]);
        o.z = f2bf(acc[e][x][y][2]); o.w = f2bf(acc[e][x][y][3]);
        *(ushort4*)(C + m * 256 + n) = o;
      }
    }
    const float* al = attn_l + (((layer * 3 + e) * 4 + h) << 6);
    const float* ar = attn_r + (((layer * 3 + e) * 4 + h) << 6);
    float4 alv[4], arv[4];
#pragma unroll
    for (int y = 0; y < 4; ++y) {
      alv[y] = *(const float4*)(al + y * 16 + quad * 4);
      arv[y] = *(const float4*)(ar + y * 16 + quad * 4);
    }
#pragma unroll
    for (int x = 0; x < 4; ++x) {
      float pl = 0.f, pr = 0.f;
#pragma unroll
      for (int y = 0; y < 4; ++y) {
        pl += acc[e][x][y][0] * alv[y].x + acc[e][x][y][1] * alv[y].y +
              acc[e][x][y][2] * alv[y].z + acc[e][x][y][3] * alv[y].w;
        pr += acc[e][x][y][0] * arv[y].x + acc[e][x][y][1] * arv[y].y +
              acc[e][x][y][2] * arv[y].z + acc[e][x][y][3] * arv[y].w;
      }
      pl += __shfl_xor(pl, 16); pl += __shfl_xor(pl, 32);
      pr += __shfl_xor(pr, 16); pr += __shfl_xor(pr, 32);
      const int m = (int)m0 + wm + x * 16 + ln;
      if (quad == 0 && m < N_NODES) {
        el[((size_t)e * N_NODES + m) * 4 + h] = pl;
        er[((size_t)e * N_NODES + m) * 4 + h] = pr;
      }
    }
  }
}

// ---------------------------------------------------------------------------
// Final classifier GEMM (fp32 out + bias, guarded).
// ---------------------------------------------------------------------------
__global__ __launch_bounds__(256) void gemm128(const ushort* __restrict__ A,
                                               const ushort* __restrict__ Bt,
                                               float* __restrict__ C,
                                               const float* __restrict__ obias,
                                               int ldc, int nmax, int mmax) {
  __shared__ ushort As[128 * 64];
  __shared__ ushort Bs[128 * 64];
  const int t = threadIdx.x;
  const int lane = t & 63;
  const int wave = t >> 6;
  const int wm = (wave >> 1) << 6;
  const int wn = (wave & 1) << 6;
  const int quad = lane >> 4;
  const int ln = lane & 15;
  const size_t m0 = (size_t)blockIdx.x * 128;
  const size_t n0 = (size_t)blockIdx.y * 128;

  f32x4 acc[4][4];
#pragma unroll
  for (int x = 0; x < 4; ++x)
#pragma unroll
    for (int y = 0; y < 4; ++y)
      acc[x][y] = (f32x4){0.f, 0.f, 0.f, 0.f};

  for (int k0 = 0; k0 < 256; k0 += 64) {
    __syncthreads();
#pragma unroll
    for (int i = 0; i < 4; ++i) {
      const int f = i * 256 + t;
      const int row = f >> 3;
      const int cl = (f & 7) ^ (row & 7);
      const int ldsbase = (i * 256 + (t & ~63)) << 3;
      __builtin_amdgcn_global_load_lds(
          (const __attribute__((address_space(1))) void*)(A + (m0 + row) * 256 + k0 + cl * 8),
          (__attribute__((address_space(3))) void*)(As + ldsbase), 16, 0, 0);
      __builtin_amdgcn_global_load_lds(
          (const __attribute__((address_space(1))) void*)(Bt + (n0 + row) * 256 + k0 + cl * 8),
          (__attribute__((address_space(3))) void*)(Bs + ldsbase), 16, 0, 0);
    }
    __syncthreads();
#pragma unroll
    for (int s = 0; s < 2; ++s) {
      bf16x8 af[4], bfr[4];
      const int cl = s * 4 + quad;
#pragma unroll
      for (int x = 0; x < 4; ++x) {
        const int mm = wm + x * 16 + ln;
        af[x] = *(const bf16x8*)(As + mm * 64 + ((cl ^ (mm & 7)) << 3));
        const int nn = wn + x * 16 + ln;
        bfr[x] = *(const bf16x8*)(Bs + nn * 64 + ((cl ^ (nn & 7)) << 3));
      }
#pragma unroll
      for (int x = 0; x < 4; ++x)
#pragma unroll
        for (int y = 0; y < 4; ++y)
          acc[x][y] = __builtin_amdgcn_mfma_f32_16x16x32_bf16(bfr[y], af[x], acc[x][y], 0, 0, 0);
    }
  }

#pragma unroll
  for (int x = 0; x < 4; ++x) {
    const int m = (int)m0 + wm + x * 16 + ln;
    if (m < mmax) {
#pragma unroll
      for (int y = 0; y < 4; ++y) {
        const int n = (int)n0 + wn + y * 16 + quad * 4;
#pragma unroll
        for (int r = 0; r < 4; ++r)
          if (n + r < nmax)
            C[(size_t)m * ldc + n + r] = acc[x][y][r] + obias[n + r];
      }
    }
  }
}

// ---------------------------------------------------------------------------
// Per-edge attention weights in CSR order (fp16). el/er total 4.8 MB ->
// L2-resident gathers; fully parallel; removes the dependent gather from agg.
// ---------------------------------------------------------------------------
__global__ __launch_bounds__(256) void wcalc_kernel(const int* __restrict__ perm,
                                                    const int* __restrict__ dstc,
                                                    const float* __restrict__ el,
                                                    const float* __restrict__ er,
                                                    ushort* __restrict__ wcsr) {
  const int i = blockIdx.x * 256 + threadIdx.x;
  if (i >= 3 * N_EDGES) return;
  const int et = i / N_EDGES;
  const int s = perm[i];
  const int d = dstc[i];
  const float4 l4 = ((const float4*)el)[(size_t)et * N_NODES + s];
  const float4 r4 = ((const float4*)er)[(size_t)et * N_NODES + d];
  float z0 = l4.x + r4.x, z1 = l4.y + r4.y, z2 = l4.z + r4.z, z3 = l4.w + r4.w;
  z0 = (z0 > 0.f) ? z0 : 0.2f * z0;
  z1 = (z1 > 0.f) ? z1 : 0.2f * z1;
  z2 = (z2 > 0.f) ? z2 : 0.2f * z2;
  z3 = (z3 > 0.f) ? z3 : 0.2f * z3;
  ushort4 o;
  o.x = __half_as_ushort(__float2half(__expf(z0)));
  o.y = __half_as_ushort(__float2half(__expf(z1)));
  o.z = __half_as_ushort(__float2half(__expf(z2)));
  o.w = __half_as_ushort(__float2half(__expf(z3)));
  ((ushort4*)wcsr)[i] = o;
}

// ---------------------------------------------------------------------------
// Aggregation v3: one wave per node, 3 etypes. All non-gather loads (perm, w)
// are sequential; 8 feat gathers per chunk are independent and issued as a
// batch. Remainder is branchless: index clamped to end-1 (dup gather = cache
// hit), weight selected to 0. agg = (sum w*feat)/(sum w).
// ---------------------------------------------------------------------------
__global__ __launch_bounds__(256) void agg_kernel(const ushort* __restrict__ feat,
                                                  const ushort* __restrict__ wcsr,
                                                  const int* __restrict__ rowp,
                                                  const int* __restrict__ perm,
                                                  const float* __restrict__ bias,
                                                  ushort* __restrict__ hout,
                                                  int layer, int do_relu) {
  const int wave = threadIdx.x >> 6, lane = threadIdx.x & 63;
  const int n = blockIdx.x * 4 + wave;
  const int h = lane >> 4;
  const float* bl = bias + layer * 768 + (lane << 2);
  float a0 = bl[0] + bl[256] + bl[512];
  float a1 = bl[1] + bl[257] + bl[513];
  float a2 = bl[2] + bl[258] + bl[514];
  float a3 = bl[3] + bl[259] + bl[515];
#pragma unroll
  for (int et = 0; et < 3; ++et) {
    const int beg = rowp[et * (N_NODES + 1) + n];
    const int end = rowp[et * (N_NODES + 1) + n + 1];
    if (end == beg) continue;                       // avoid 0/0 on isolated nodes
    const int* ps = perm + (size_t)et * N_EDGES;
    const ushort* wc = wcsr + (size_t)et * N_EDGES * 4;
    const ushort* fb = feat + (size_t)et * M_PAD * 256;
    const int last = end - 1;
    float l0 = 0.f, l1 = 0.f, l2 = 0.f, l3 = 0.f, den = 0.f;
    for (int i = beg; i < end; i += 8) {
      int idx[8];
#pragma unroll
      for (int j = 0; j < 8; ++j)
        idx[j] = (i + j < last) ? (i + j) : last;   // clamp: always valid
      int sj[8];
#pragma unroll
      for (int j = 0; j < 8; ++j)
        sj[j] = ps[idx[j]];
      float wj[8];
#pragma unroll
      for (int j = 0; j < 8; ++j) {
        const float t = __half2float(__ushort_as_half(wc[idx[j] * 4 + h]));
        wj[j] = (i + j <= last) ? t : 0.f;          // branchless remainder
      }
      ushort4 fv[8];
#pragma unroll
      for (int j = 0; j < 8; ++j)
        fv[j] = *(const ushort4*)(fb + (size_t)sj[j] * 256 + (lane << 2));
#pragma unroll
      for (int j = 0; j < 8; ++j) {
        den += wj[j];
        l0 += wj[j] * bf2f(fv[j].x); l1 += wj[j] * bf2f(fv[j].y);
        l2 += wj[j] * bf2f(fv[j].z); l3 += wj[j] * bf2f(fv[j].w);
      }
    }
    const float inv = 1.0f / den;
    a0 += l0 * inv; a1 += l1 * inv; a2 += l2 * inv; a3 += l3 * inv;
  }
  if (do_relu) {
    a0 = fmaxf(a0, 0.f); a1 = fmaxf(a1, 0.f);
    a2 = fmaxf(a2, 0.f); a3 = fmaxf(a3, 0.f);
  }
  ushort4 o;
  o.x = f2bf(a0); o.y = f2bf(a1); o.z = f2bf(a2); o.w = f2bf(a3);
  *(ushort4*)(hout + (size_t)n * 256 + (lane << 2)) = o;
}

// ---------------------------------------------------------------------------
extern "C" void kernel_launch(void* const* d_in, const int* in_sizes, int n_in,
                              void* d_out, int out_size, void* d_ws, size_t ws_size,
                              hipStream_t stream) {
  const float* x      = (const float*)d_in[0];
  const float* W      = (const float*)d_in[1];
  const float* attn_l = (const float*)d_in[2];
  const float* attn_r = (const float*)d_in[3];
  const float* bias   = (const float*)d_in[4];
  const float* W_out  = (const float*)d_in[5];
  const float* b_out  = (const float*)d_in[6];
  const int*   src    = (const int*)d_in[7];
  const int*   dst    = (const int*)d_in[8];

  char* p = (char*)d_ws;
  auto carve = [&](size_t bytes) {
    char* r = p;
    p += (bytes + 255) & ~(size_t)255;
    return r;
  };
  ushort* h_bf  = (ushort*)carve((size_t)M_PAD * 256 * 2);        //  51.2 MB
  ushort* feat  = (ushort*)carve((size_t)3 * M_PAD * 256 * 2);    // 153.7 MB
  ushort* Wt    = (ushort*)carve((size_t)6 * 65536 * 2);
  ushort* Wto   = (ushort*)carve((size_t)384 * 256 * 2);
  float*  el    = (float*)carve((size_t)3 * N_NODES * 4 * 4);
  float*  er    = (float*)carve((size_t)3 * N_NODES * 4 * 4);
  int*    cnt   = (int*)carve((size_t)3 * N_NODES * 4);
  int*    rowp  = (int*)carve((size_t)3 * (N_NODES + 1) * 4);
  int*    cur   = (int*)carve((size_t)3 * N_NODES * 4);
  int*    perm  = (int*)carve((size_t)3 * N_EDGES * 4);           //   6 MB
  int*    dstc  = (int*)carve((size_t)3 * N_EDGES * 4);           //   6 MB
  ushort* wcsr  = (ushort*)carve((size_t)3 * N_EDGES * 4 * 2);    //  12 MB (fp16)
  int*    bsum  = (int*)carve((size_t)3 * NCHUNK * 4);

  cvt_x_kernel<<<M_PAD * 64 / 256, 256, 0, stream>>>(x, h_bf);
  cvt_w_kernel<<<6 * 65536 / 256, 256, 0, stream>>>(W, Wt);
  cvt_wout_kernel<<<384 * 256 / 256, 256, 0, stream>>>(W_out, Wto);

  zero_cnt_kernel<<<(3 * N_NODES + 255) / 256, 256, 0, stream>>>(cnt);
  hist_kernel<<<(3 * N_EDGES + 255) / 256, 256, 0, stream>>>(dst, cnt);
  scan1_kernel<<<dim3(NCHUNK, 3), 512, 0, stream>>>(cnt, rowp, bsum);
  scan2_kernel<<<3, 256, 0, stream>>>(bsum);
  scan3_kernel<<<dim3(NCHUNK, 3), 512, 0, stream>>>(rowp, bsum, cur);
  scatter_kernel<<<(3 * N_EDGES + 255) / 256, 256, 0, stream>>>(src, dst, cur, perm, dstc);

  for (int l = 0; l < 2; ++l) {
    gemm_feat_fused<<<dim3(M_PAD / 128, 2), 256, 0, stream>>>(
        h_bf, Wt + (size_t)l * 3 * 65536, feat, attn_l, attn_r, el, er, l);
    wcalc_kernel<<<(3 * N_EDGES + 255) / 256, 256, 0, stream>>>(perm, dstc, el, er, wcsr);
    agg_kernel<<<N_NODES / 4, 256, 0, stream>>>(feat, wcsr, rowp, perm, bias,
                                                h_bf, l, l == 0 ? 1 : 0);
  }
  gemm128<<<dim3(M_PAD / 128, 3), 256, 0, stream>>>(h_bf, Wto, (float*)d_out,
                                                    b_out, 349, 349, N_NODES);
}